// Round 5
// baseline (13760.278 us; speedup 1.0000x reference)
//
#include <hip/hip_runtime.h>
#include <math.h>

#define B_    8
#define P_    8192
#define M_    2048
#define NNODE 16384      // B_*M_
#define NCOL  524288     // NNODE*32
#define EPS_  1e-5f

// ---- ws layout (bytes) ----
#define OFF_SX   0ull                        // 65536 f32 = 262144
#define OFF_KNN  (OFF_SX + 262144ull)        // 524288 i32 = 2097152
#define OFF_FT   (OFF_KNN + 2097152ull)      // 8*8192*64 f32 = 16777216
#define OFF_ST   (OFF_FT + 16777216ull)      // 768 f32 (pad 4096)
#define OFF_AF   (OFF_ST + 4096ull)          // 768 f32 (pad 4096)
#define OFF_W0   (OFF_AF + 4096ull)          // 67*64 f32 = 17152
#define OFF_W1   (OFF_W0 + 17152ull)         // 64*64 f32 = 16384
#define OFF_W2   (OFF_W1 + 16384ull)         // 64*128 f32 = 32768
#define OFF_Y1   (OFF_W2 + 32768ull)         // 524288*64 f32 = 134217728
// total ~147 MB

// ---------------- prep ----------------
__global__ __launch_bounds__(256) void k_prep(
    const float* __restrict__ xyz, const float* __restrict__ W0,
    const float* __restrict__ W1, const float* __restrict__ W2,
    float* __restrict__ sx, float* __restrict__ Wt0, float* __restrict__ Wt1,
    float* __restrict__ Wt2, float* __restrict__ stats, float* __restrict__ centers_out)
{
  int idx = blockIdx.x*256 + threadIdx.x;
  if (idx < B_*P_) {
    const float* p3 = xyz + (size_t)idx*3;
    float x = p3[0], y = p3[1], z = p3[2];
    // reference-shared f32: fl(fl(x^2 + y^2) + z^2), no FMA (np ufunc semantics)
    sx[idx] = __fadd_rn(__fadd_rn(__fmul_rn(x,x), __fmul_rn(y,y)), __fmul_rn(z,z));
  }
  if (idx < NNODE*3) {
    int m2 = idx/3, comp = idx - m2*3;
    int b = m2 >> 11, m = m2 & 2047;
    int cp = (m * 8191) / 2047;   // exact floor == int32(linspace), verified (output 0 passes)
    centers_out[idx] = xyz[((size_t)(b*P_ + cp))*3 + comp];
  }
  if (idx < 67*64) { int c = idx >> 6, o = idx & 63;  Wt0[idx] = W0[o*67 + c]; }
  if (idx < 64*64) { int c = idx >> 6, o = idx & 63;  Wt1[idx] = W1[o*64 + c]; }
  if (idx < 64*128){ int c = idx >> 7, o = idx & 127; Wt2[idx] = W2[o*64 + c]; }
  if (idx < 768)   stats[idx] = 0.f;
}

// ---------------- feats (b,c,p) -> ft (b,p,c) ----------------
__global__ __launch_bounds__(256) void k_ft(const float* __restrict__ feats, float* __restrict__ ft)
{
  int blk = blockIdx.x;            // 8*128
  int b = blk >> 7; int pt = (blk & 127) * 64;
  __shared__ float tile[64][65];
  const float* fb = feats + (size_t)b*64*P_;
  int tid = threadIdx.x;
  #pragma unroll
  for (int i = 0; i < 16; ++i) {
    int idx = i*256 + tid; int c = idx >> 6, p = idx & 63;
    tile[c][p] = fb[(size_t)c*P_ + pt + p];
  }
  __syncthreads();
  float* fo = ft + ((size_t)b*P_ + pt)*64;
  #pragma unroll
  for (int i = 0; i < 16; ++i) {
    int idx = i*256 + tid; int p = idx >> 6, c = idx & 63;
    fo[(size_t)p*64 + c] = tile[c][p];
  }
}

// ---------------- KNN: reference-shared f32 pipeline with FMA-chain dot ----------------
// d2 = fl( fl(sc + sx[p]) - fl(2 * dot) ),  dot = fma(cz,pz, fma(cy,py, cx*px))
// (np.einsum inner loop compiled with fp-contract=fast and XLA's dot emitter both
//  produce the forward FMA chain; sc/sx are separate no-FMA ufunc passes.)
// Selection: ascending (d2, index) — lax.top_k tie semantics.
__global__ __launch_bounds__(256) void k_knn(const float* __restrict__ xyz,
                                             const float* __restrict__ sx,
                                             int* __restrict__ knn)
{
  const int tid = threadIdx.x;
  const int lane = tid & 63, wid = tid >> 6;
  __shared__ float wv[4]; __shared__ int wg[4];
  int c0 = blockIdx.x * 4;
  for (int cc = 0; cc < 4; ++cc) {
    int cid = c0 + cc;
    int b = cid >> 11, m = cid & 2047;
    int cp = (m * 8191) / 2047;
    const float* xb  = xyz + (size_t)b * P_ * 3;
    const float* sxb = sx + b * P_;
    float cx = xb[cp*3+0], cy = xb[cp*3+1], cz = xb[cp*3+2];
    float sc = sxb[cp];
    float fkey[32];
    #pragma unroll
    for (int i = 0; i < 32; ++i) {
      int p = i*256 + tid;
      float px = xb[p*3+0], py = xb[p*3+1], pz = xb[p*3+2];
      float dot = fmaf(cz, pz, fmaf(cy, py, __fmul_rn(cx, px)));
      fkey[i] = __fsub_rn(__fadd_rn(sc, sxb[p]), __fmul_rn(2.0f, dot));
    }
    unsigned rem = 0u;
    float bv = INFINITY; int bp = 0x7FFFFFFF;
    #pragma unroll
    for (int i = 0; i < 32; ++i)
      if (fkey[i] < bv) { bv = fkey[i]; bp = i*256 + tid; }   // ascending scan keeps lowest index on ties
    for (int r = 0; r < 32; ++r) {
      float v = bv; int g = bp;
      #pragma unroll
      for (int off = 32; off > 0; off >>= 1) {
        float ov = __shfl_down(v, off, 64);
        int   og = __shfl_down(g, off, 64);
        if (ov < v || (ov == v && og < g)) { v = ov; g = og; }
      }
      __syncthreads();
      if (lane == 0) { wv[wid] = v; wg[wid] = g; }
      __syncthreads();
      v = wv[0]; g = wg[0];
      #pragma unroll
      for (int w = 1; w < 4; ++w) {
        float ov = wv[w]; int og = wg[w];
        if (ov < v || (ov == v && og < g)) { v = ov; g = og; }
      }
      if (tid == 0) knn[cid*32 + r] = g;
      if ((g & 255) == tid) {
        rem |= 1u << (g >> 8);
        bv = INFINITY; bp = 0x7FFFFFFF;
        #pragma unroll
        for (int i = 0; i < 32; ++i)
          if (!(rem & (1u<<i)) && fkey[i] < bv) { bv = fkey[i]; bp = i*256 + tid; }
      }
    }
  }
}

// ---------------- shared conv pieces ----------------
__device__ __forceinline__ void conv0_col(
    const float* __restrict__ xyz, const float* __restrict__ ft,
    const float* __restrict__ Wt0, const float* __restrict__ b0,
    int b, int p, float acc[64])
{
  #pragma unroll
  for (int o = 0; o < 64; ++o) acc[o] = b0[o];
  const float* xp = xyz + ((size_t)(b*P_ + p))*3;
  float xs3[3] = {xp[0], xp[1], xp[2]};
  #pragma unroll
  for (int c = 0; c < 3; ++c)
    #pragma unroll
    for (int o = 0; o < 64; ++o) acc[o] = fmaf(Wt0[c*64+o], xs3[c], acc[o]);
  const float* fp = ft + ((size_t)(b*P_ + p))*64;
  #pragma unroll
  for (int c4 = 0; c4 < 64; c4 += 4) {
    float4 xv = *(const float4*)(fp + c4);
    float xs[4] = {xv.x, xv.y, xv.z, xv.w};
    #pragma unroll
    for (int u = 0; u < 4; ++u)
      #pragma unroll
      for (int o = 0; o < 64; ++o) acc[o] = fmaf(Wt0[(3+c4+u)*64+o], xs[u], acc[o]);
  }
}

// per-wave -> LDS -> global stats accumulation for C channels
template<int C>
__device__ __forceinline__ void stats_reduce(const float* acc, int tid, int lane,
                                             float* lsum, float* lsq, float* statsg)
{
  #pragma unroll
  for (int o = 0; o < C; ++o) {
    float v = acc[o], q = v*v;
    #pragma unroll
    for (int off = 1; off < 64; off <<= 1) {
      v += __shfl_xor(v, off, 64);
      q += __shfl_xor(q, off, 64);
    }
    if (lane == 0) { atomicAdd(&lsum[o], v); atomicAdd(&lsq[o], q); }
  }
  __syncthreads();
  if (tid < C) { atomicAdd(&statsg[tid], lsum[tid]); atomicAdd(&statsg[128+tid], lsq[tid]); }
}

// ---------------- pass 1: conv0 -> stats0 (no store) ----------------
__global__ __launch_bounds__(256) void k_stat0(
    const float* __restrict__ xyz, const float* __restrict__ ft,
    const int* __restrict__ knn, const float* __restrict__ Wt0,
    const float* __restrict__ b0, float* __restrict__ stats0)
{
  __shared__ float lsum[64], lsq[64];
  int tid = threadIdx.x, lane = tid & 63;
  if (tid < 64) { lsum[tid] = 0.f; lsq[tid] = 0.f; }
  __syncthreads();
  int col = blockIdx.x*256 + tid;
  int node = col >> 5, b = node >> 11, p = knn[col];
  float acc[64];
  conv0_col(xyz, ft, Wt0, b0, b, p, acc);
  stats_reduce<64>(acc, tid, lane, lsum, lsq, stats0);
}

// ---------------- pass 2: conv0 -> bn0/relu -> conv1 -> y1 (f32) + stats1 ----------------
__global__ __launch_bounds__(256) void k_l01(
    const float* __restrict__ xyz, const float* __restrict__ ft,
    const int* __restrict__ knn, const float* __restrict__ Wt0,
    const float* __restrict__ b0, const float* __restrict__ aff0,
    const float* __restrict__ Wt1, const float* __restrict__ b1,
    float* __restrict__ y1, float* __restrict__ stats1)
{
  __shared__ float lsum[64], lsq[64];
  int tid = threadIdx.x, lane = tid & 63;
  if (tid < 64) { lsum[tid] = 0.f; lsq[tid] = 0.f; }
  __syncthreads();
  int col = blockIdx.x*256 + tid;
  int node = col >> 5, b = node >> 11, p = knn[col];
  float acc0[64];
  conv0_col(xyz, ft, Wt0, b0, b, p, acc0);
  #pragma unroll
  for (int c = 0; c < 64; ++c)
    acc0[c] = fmaxf(fmaf(acc0[c], aff0[c], aff0[128+c]), 0.f);
  float acc1[64];
  #pragma unroll
  for (int o = 0; o < 64; ++o) acc1[o] = b1[o];
  #pragma unroll
  for (int c = 0; c < 64; ++c)
    #pragma unroll
    for (int o = 0; o < 64; ++o) acc1[o] = fmaf(Wt1[c*64+o], acc0[c], acc1[o]);
  float* yrow = y1 + (size_t)col*64;
  #pragma unroll
  for (int c4 = 0; c4 < 64; c4 += 4)
    *(float4*)(yrow + c4) = make_float4(acc1[c4], acc1[c4+1], acc1[c4+2], acc1[c4+3]);
  stats_reduce<64>(acc1, tid, lane, lsum, lsq, stats1);
}

// ---------------- pass 3: y1 -> bn1/relu -> conv2 -> stats2 (no store) ----------------
__global__ __launch_bounds__(256) void k_stat2(
    const float* __restrict__ y1, const float* __restrict__ aff1,
    const float* __restrict__ Wt2, const float* __restrict__ b2,
    float* __restrict__ stats2)
{
  __shared__ float lsum[128], lsq[128];
  int tid = threadIdx.x, lane = tid & 63;
  if (tid < 128) { lsum[tid] = 0.f; lsq[tid] = 0.f; }
  __syncthreads();
  int col = blockIdx.x*256 + tid;
  const float* yrow = y1 + (size_t)col*64;
  float x[64];
  #pragma unroll
  for (int c4 = 0; c4 < 64; c4 += 4) {
    float4 v = *(const float4*)(yrow + c4);
    x[c4]   = fmaxf(fmaf(v.x, aff1[c4],   aff1[128+c4]),   0.f);
    x[c4+1] = fmaxf(fmaf(v.y, aff1[c4+1], aff1[128+c4+1]), 0.f);
    x[c4+2] = fmaxf(fmaf(v.z, aff1[c4+2], aff1[128+c4+2]), 0.f);
    x[c4+3] = fmaxf(fmaf(v.w, aff1[c4+3], aff1[128+c4+3]), 0.f);
  }
  float acc[128];
  #pragma unroll
  for (int o = 0; o < 128; ++o) acc[o] = b2[o];
  #pragma unroll
  for (int c = 0; c < 64; ++c)
    #pragma unroll
    for (int o = 0; o < 128; ++o) acc[o] = fmaf(Wt2[c*128+o], x[c], acc[o]);
  stats_reduce<128>(acc, tid, lane, lsum, lsq, stats2);
}

// ---------------- BN finalize ----------------
__global__ void k_fin(const float* __restrict__ stats, const float* __restrict__ g,
                      const float* __restrict__ be, float* __restrict__ aff, int C)
{
  int o = threadIdx.x;
  if (o < C) {
    float N = (float)NCOL;
    float mu = stats[o] / N;
    float var = stats[128+o]/N - mu*mu;
    float r = 1.0f / sqrtf(var + EPS_);
    float s = g[o]*r;
    aff[o] = s;
    aff[128+o] = fmaf(-mu, s, be[o]);
  }
}

// ---------------- pass 4: y1 -> bn1/relu -> conv2 -> bn2/relu -> max_k -> out ----------------
__global__ __launch_bounds__(256) void k_maxout(
    const float* __restrict__ y1, const float* __restrict__ aff1,
    const float* __restrict__ Wt2, const float* __restrict__ b2,
    const float* __restrict__ aff2, float* __restrict__ out)
{
  int tid = threadIdx.x;
  int j = tid & 31;                       // sample within node
  int node = blockIdx.x*8 + (tid >> 5);   // 8 nodes per block
  int col = node*32 + j;
  const float* yrow = y1 + (size_t)col*64;
  float x[64];
  #pragma unroll
  for (int c4 = 0; c4 < 64; c4 += 4) {
    float4 v = *(const float4*)(yrow + c4);
    x[c4]   = fmaxf(fmaf(v.x, aff1[c4],   aff1[128+c4]),   0.f);
    x[c4+1] = fmaxf(fmaf(v.y, aff1[c4+1], aff1[128+c4+1]), 0.f);
    x[c4+2] = fmaxf(fmaf(v.z, aff1[c4+2], aff1[128+c4+2]), 0.f);
    x[c4+3] = fmaxf(fmaf(v.w, aff1[c4+3], aff1[128+c4+3]), 0.f);
  }
  float acc[128];
  #pragma unroll
  for (int o = 0; o < 128; ++o) acc[o] = b2[o];
  #pragma unroll
  for (int c = 0; c < 64; ++c)
    #pragma unroll
    for (int o = 0; o < 128; ++o) acc[o] = fmaf(Wt2[c*128+o], x[c], acc[o]);
  int b = node >> 11, m = node & 2047;
  float* op = out + ((size_t)b*128)*2048 + m;
  #pragma unroll
  for (int o = 0; o < 128; ++o) {
    float v = fmaxf(fmaf(acc[o], aff2[o], aff2[128+o]), 0.f);
    #pragma unroll
    for (int off = 1; off < 32; off <<= 1)
      v = fmaxf(v, __shfl_xor(v, off, 64));
    if (j == 0) op[(size_t)o*2048] = v;
  }
}

extern "C" void kernel_launch(void* const* d_in, const int* in_sizes, int n_in,
                              void* d_out, int out_size, void* d_ws, size_t ws_size,
                              hipStream_t stream)
{
  const float* xyz   = (const float*)d_in[0];
  const float* feats = (const float*)d_in[1];
  const float* W0 = (const float*)d_in[2];
  const float* b0 = (const float*)d_in[3];
  const float* g0 = (const float*)d_in[4];
  const float* be0= (const float*)d_in[5];
  const float* W1 = (const float*)d_in[6];
  const float* b1 = (const float*)d_in[7];
  const float* g1 = (const float*)d_in[8];
  const float* be1= (const float*)d_in[9];
  const float* W2 = (const float*)d_in[10];
  const float* b2 = (const float*)d_in[11];
  const float* g2 = (const float*)d_in[12];
  const float* be2= (const float*)d_in[13];

  char* ws = (char*)d_ws;
  float* sx    = (float*)(ws + OFF_SX);
  int*   knn   = (int*  )(ws + OFF_KNN);
  float* ft    = (float*)(ws + OFF_FT);
  float* stats = (float*)(ws + OFF_ST);
  float* aff   = (float*)(ws + OFF_AF);
  float* Wt0   = (float*)(ws + OFF_W0);
  float* Wt1   = (float*)(ws + OFF_W1);
  float* Wt2   = (float*)(ws + OFF_W2);
  float* y1    = (float*)(ws + OFF_Y1);

  float* centers_out = (float*)d_out;              // 8*2048*3
  float* feat_out    = (float*)d_out + NNODE*3;    // 8*128*2048

  k_prep<<<256, 256, 0, stream>>>(xyz, W0, W1, W2, sx, Wt0, Wt1, Wt2, stats, centers_out);
  k_ft  <<<1024, 256, 0, stream>>>(feats, ft);
  k_knn <<<NNODE/4, 256, 0, stream>>>(xyz, sx, knn);
  k_stat0<<<NCOL/256, 256, 0, stream>>>(xyz, ft, knn, Wt0, b0, stats + 0);
  k_fin  <<<1, 128, 0, stream>>>(stats + 0,   g0, be0, aff + 0,   64);
  k_l01  <<<NCOL/256, 256, 0, stream>>>(xyz, ft, knn, Wt0, b0, aff + 0, Wt1, b1, y1, stats + 256);
  k_fin  <<<1, 128, 0, stream>>>(stats + 256, g1, be1, aff + 256, 64);
  k_stat2<<<NCOL/256, 256, 0, stream>>>(y1, aff + 256, Wt2, b2, stats + 512);
  k_fin  <<<1, 128, 0, stream>>>(stats + 512, g2, be2, aff + 512, 128);
  k_maxout<<<NNODE/8, 256, 0, stream>>>(y1, aff + 256, Wt2, b2, aff + 512, feat_out);
}

// Round 6
// 11337.453 us; speedup vs baseline: 1.2137x; 1.2137x over previous
//
#include <hip/hip_runtime.h>
#include <math.h>

#define B_    8
#define P_    8192
#define M_    2048
#define NNODE 16384      // B_*M_
#define NCOL  524288     // NNODE*32
#define EPS_  1e-5f

// ---- ws layout (bytes) ----
#define OFF_SX   0ull                        // 65536 f32 = 262144
#define OFF_KNN  (OFF_SX + 262144ull)        // 524288 i32 = 2097152
#define OFF_FT   (OFF_KNN + 2097152ull)      // 8*8192*64 f32 = 16777216
#define OFF_ST   (OFF_FT + 16777216ull)      // 768 f32 (pad 4096)
#define OFF_AF   (OFF_ST + 4096ull)          // 768 f32 (pad 4096)
#define OFF_W0   (OFF_AF + 4096ull)          // 67*64 f32 = 17152
#define OFF_W1   (OFF_W0 + 17152ull)         // 64*64 f32 = 16384
#define OFF_W2   (OFF_W1 + 16384ull)         // 64*128 f32 = 32768
#define OFF_Y1   (OFF_W2 + 32768ull)         // 524288*64 f32 = 134217728
// total ~147 MB

// ---------------- prep ----------------
__global__ __launch_bounds__(256) void k_prep(
    const float* __restrict__ xyz, const float* __restrict__ W0,
    const float* __restrict__ W1, const float* __restrict__ W2,
    float* __restrict__ sx, float* __restrict__ Wt0, float* __restrict__ Wt1,
    float* __restrict__ Wt2, float* __restrict__ stats, float* __restrict__ centers_out)
{
  int idx = blockIdx.x*256 + threadIdx.x;
  if (idx < B_*P_) {
    const float* p3 = xyz + (size_t)idx*3;
    float x = p3[0], y = p3[1], z = p3[2];
    sx[idx] = __fadd_rn(__fadd_rn(__fmul_rn(x,x), __fmul_rn(y,y)), __fmul_rn(z,z));
  }
  if (idx < NNODE*3) {
    int m2 = idx/3, comp = idx - m2*3;
    int b = m2 >> 11, m = m2 & 2047;
    int cp = (m * 8191) / 2047;   // exact floor == int32(linspace), verified
    centers_out[idx] = xyz[((size_t)(b*P_ + cp))*3 + comp];
  }
  if (idx < 67*64) { int c = idx >> 6, o = idx & 63;  Wt0[idx] = W0[o*67 + c]; }
  if (idx < 64*64) { int c = idx >> 6, o = idx & 63;  Wt1[idx] = W1[o*64 + c]; }
  if (idx < 64*128){ int c = idx >> 7, o = idx & 127; Wt2[idx] = W2[o*64 + c]; }
  if (idx < 768)   stats[idx] = 0.f;
}

// ---------------- feats (b,c,p) -> ft (b,p,c) ----------------
__global__ __launch_bounds__(256) void k_ft(const float* __restrict__ feats, float* __restrict__ ft)
{
  int blk = blockIdx.x;            // 8*128
  int b = blk >> 7; int pt = (blk & 127) * 64;
  __shared__ float tile[64][65];
  const float* fb = feats + (size_t)b*64*P_;
  int tid = threadIdx.x;
  #pragma unroll
  for (int i = 0; i < 16; ++i) {
    int idx = i*256 + tid; int c = idx >> 6, p = idx & 63;
    tile[c][p] = fb[(size_t)c*P_ + pt + p];
  }
  __syncthreads();
  float* fo = ft + ((size_t)b*P_ + pt)*64;
  #pragma unroll
  for (int i = 0; i < 16; ++i) {
    int idx = i*256 + tid; int p = idx >> 6, c = idx & 63;
    fo[(size_t)p*64 + c] = tile[c][p];
  }
}

// ---------------- KNN: VERIFIED BIT-MATCHED — DO NOT TOUCH ----------------
__global__ __launch_bounds__(256) void k_knn(const float* __restrict__ xyz,
                                             const float* __restrict__ sx,
                                             int* __restrict__ knn)
{
  const int tid = threadIdx.x;
  const int lane = tid & 63, wid = tid >> 6;
  __shared__ float wv[4]; __shared__ int wg[4];
  int c0 = blockIdx.x * 4;
  for (int cc = 0; cc < 4; ++cc) {
    int cid = c0 + cc;
    int b = cid >> 11, m = cid & 2047;
    int cp = (m * 8191) / 2047;
    const float* xb  = xyz + (size_t)b * P_ * 3;
    const float* sxb = sx + b * P_;
    float cx = xb[cp*3+0], cy = xb[cp*3+1], cz = xb[cp*3+2];
    float sc = sxb[cp];
    float fkey[32];
    #pragma unroll
    for (int i = 0; i < 32; ++i) {
      int p = i*256 + tid;
      float px = xb[p*3+0], py = xb[p*3+1], pz = xb[p*3+2];
      float dot = fmaf(cz, pz, fmaf(cy, py, __fmul_rn(cx, px)));
      fkey[i] = __fsub_rn(__fadd_rn(sc, sxb[p]), __fmul_rn(2.0f, dot));
    }
    unsigned rem = 0u;
    float bv = INFINITY; int bp = 0x7FFFFFFF;
    #pragma unroll
    for (int i = 0; i < 32; ++i)
      if (fkey[i] < bv) { bv = fkey[i]; bp = i*256 + tid; }
    for (int r = 0; r < 32; ++r) {
      float v = bv; int g = bp;
      #pragma unroll
      for (int off = 32; off > 0; off >>= 1) {
        float ov = __shfl_down(v, off, 64);
        int   og = __shfl_down(g, off, 64);
        if (ov < v || (ov == v && og < g)) { v = ov; g = og; }
      }
      __syncthreads();
      if (lane == 0) { wv[wid] = v; wg[wid] = g; }
      __syncthreads();
      v = wv[0]; g = wg[0];
      #pragma unroll
      for (int w = 1; w < 4; ++w) {
        float ov = wv[w]; int og = wg[w];
        if (ov < v || (ov == v && og < g)) { v = ov; g = og; }
      }
      if (tid == 0) knn[cid*32 + r] = g;
      if ((g & 255) == tid) {
        rem |= 1u << (g >> 8);
        bv = INFINITY; bp = 0x7FFFFFFF;
        #pragma unroll
        for (int i = 0; i < 32; ++i)
          if (!(rem & (1u<<i)) && fkey[i] < bv) { bv = fkey[i]; bp = i*256 + tid; }
      }
    }
  }
}

// ---------------- helpers ----------------
// wave butterfly sum/sumsq for a 32-channel register tile -> LDS accumulators
__device__ __forceinline__ void wave_stats32(const float* acc, int lane,
                                             float* lsum, float* lsq, int off)
{
  #pragma unroll
  for (int o = 0; o < 32; ++o) {
    float v = acc[o], q = v*v;
    #pragma unroll
    for (int s = 1; s < 64; s <<= 1) {
      v += __shfl_xor(v, s, 64);
      q += __shfl_xor(q, s, 64);
    }
    if (lane == 0) { atomicAdd(&lsum[off+o], v); atomicAdd(&lsq[off+o], q); }
  }
}

// conv0 for one column: acc[64] over 67 inputs (3 xyz + 64 ft), c ascending
__device__ __forceinline__ void conv0_col(
    const float* __restrict__ xyz, const float* __restrict__ ft,
    const float* __restrict__ Wt0, const float* __restrict__ b0,
    int b, int p, float acc[64])
{
  #pragma unroll
  for (int o = 0; o < 64; ++o) acc[o] = b0[o];
  const float* xp = xyz + ((size_t)(b*P_ + p))*3;
  float xs3[3] = {xp[0], xp[1], xp[2]};
  #pragma unroll
  for (int c = 0; c < 3; ++c)
    #pragma unroll
    for (int o = 0; o < 64; ++o) acc[o] = fmaf(Wt0[c*64+o], xs3[c], acc[o]);
  const float* fp = ft + ((size_t)(b*P_ + p))*64;
  #pragma unroll
  for (int c4 = 0; c4 < 64; c4 += 4) {
    float4 xv = *(const float4*)(fp + c4);
    float xs[4] = {xv.x, xv.y, xv.z, xv.w};
    #pragma unroll
    for (int u = 0; u < 4; ++u)
      #pragma unroll
      for (int o = 0; o < 64; ++o) acc[o] = fmaf(Wt0[(3+c4+u)*64+o], xs[u], acc[o]);
  }
}

// ---------------- pass 1: conv0 -> stats0 ----------------
__global__ __launch_bounds__(256, 4) void k_stat0(
    const float* __restrict__ xyz, const float* __restrict__ ft,
    const int* __restrict__ knn, const float* __restrict__ Wt0,
    const float* __restrict__ b0, float* __restrict__ stats0)
{
  __shared__ float lsum[64], lsq[64];
  int tid = threadIdx.x, lane = tid & 63;
  if (tid < 64) { lsum[tid] = 0.f; lsq[tid] = 0.f; }
  __syncthreads();
  int col = blockIdx.x*256 + tid;
  int node = col >> 5, b = node >> 11, p = knn[col];
  float acc[64];
  conv0_col(xyz, ft, Wt0, b0, b, p, acc);
  wave_stats32(acc,      lane, lsum, lsq, 0);
  wave_stats32(acc + 32, lane, lsum, lsq, 32);
  __syncthreads();
  if (tid < 64) { atomicAdd(&stats0[tid], lsum[tid]); atomicAdd(&stats0[128+tid], lsq[tid]); }
}

// ---------------- pass 2: conv0 -> bn0/relu -> conv1 (2 o-tiles) -> y1 + stats1 ----------------
__global__ __launch_bounds__(256, 4) void k_l01(
    const float* __restrict__ xyz, const float* __restrict__ ft,
    const int* __restrict__ knn, const float* __restrict__ Wt0,
    const float* __restrict__ b0, const float* __restrict__ aff0,
    const float* __restrict__ Wt1, const float* __restrict__ b1,
    float* __restrict__ y1, float* __restrict__ stats1)
{
  __shared__ float lsum[64], lsq[64];
  int tid = threadIdx.x, lane = tid & 63;
  if (tid < 64) { lsum[tid] = 0.f; lsq[tid] = 0.f; }
  __syncthreads();
  int col = blockIdx.x*256 + tid;
  int node = col >> 5, b = node >> 11, p = knn[col];
  float x[64];
  conv0_col(xyz, ft, Wt0, b0, b, p, x);
  #pragma unroll
  for (int c = 0; c < 64; ++c)
    x[c] = fmaxf(fmaf(x[c], aff0[c], aff0[128+c]), 0.f);
  float* yrow = y1 + (size_t)col*64;
  #pragma unroll
  for (int ot = 0; ot < 2; ++ot) {
    float acc[32];
    #pragma unroll
    for (int o = 0; o < 32; ++o) acc[o] = b1[ot*32 + o];
    #pragma unroll
    for (int c = 0; c < 64; ++c)
      #pragma unroll
      for (int o = 0; o < 32; ++o) acc[o] = fmaf(Wt1[c*64 + ot*32 + o], x[c], acc[o]);
    #pragma unroll
    for (int c4 = 0; c4 < 32; c4 += 4)
      *(float4*)(yrow + ot*32 + c4) = make_float4(acc[c4], acc[c4+1], acc[c4+2], acc[c4+3]);
    wave_stats32(acc, lane, lsum, lsq, ot*32);
  }
  __syncthreads();
  if (tid < 64) { atomicAdd(&stats1[tid], lsum[tid]); atomicAdd(&stats1[128+tid], lsq[tid]); }
}

// ---------------- pass 3: y1 -> bn1/relu -> conv2 (4 o-tiles) -> stats2 ----------------
__global__ __launch_bounds__(256, 4) void k_stat2(
    const float* __restrict__ y1, const float* __restrict__ aff1,
    const float* __restrict__ Wt2, const float* __restrict__ b2,
    float* __restrict__ stats2)
{
  __shared__ float lsum[128], lsq[128];
  int tid = threadIdx.x, lane = tid & 63;
  if (tid < 128) { lsum[tid] = 0.f; lsq[tid] = 0.f; }
  __syncthreads();
  int col = blockIdx.x*256 + tid;
  const float* yrow = y1 + (size_t)col*64;
  float x[64];
  #pragma unroll
  for (int c4 = 0; c4 < 64; c4 += 4) {
    float4 v = *(const float4*)(yrow + c4);
    x[c4]   = fmaxf(fmaf(v.x, aff1[c4],   aff1[128+c4]),   0.f);
    x[c4+1] = fmaxf(fmaf(v.y, aff1[c4+1], aff1[128+c4+1]), 0.f);
    x[c4+2] = fmaxf(fmaf(v.z, aff1[c4+2], aff1[128+c4+2]), 0.f);
    x[c4+3] = fmaxf(fmaf(v.w, aff1[c4+3], aff1[128+c4+3]), 0.f);
  }
  #pragma unroll
  for (int ot = 0; ot < 4; ++ot) {
    float acc[32];
    #pragma unroll
    for (int o = 0; o < 32; ++o) acc[o] = b2[ot*32 + o];
    #pragma unroll
    for (int c = 0; c < 64; ++c)
      #pragma unroll
      for (int o = 0; o < 32; ++o) acc[o] = fmaf(Wt2[c*128 + ot*32 + o], x[c], acc[o]);
    wave_stats32(acc, lane, lsum, lsq, ot*32);
  }
  __syncthreads();
  if (tid < 128) { atomicAdd(&stats2[tid], lsum[tid]); atomicAdd(&stats2[128+tid], lsq[tid]); }
}

// ---------------- BN finalize ----------------
__global__ void k_fin(const float* __restrict__ stats, const float* __restrict__ g,
                      const float* __restrict__ be, float* __restrict__ aff, int C)
{
  int o = threadIdx.x;
  if (o < C) {
    float N = (float)NCOL;
    float mu = stats[o] / N;
    float var = stats[128+o]/N - mu*mu;
    float r = 1.0f / sqrtf(var + EPS_);
    float s = g[o]*r;
    aff[o] = s;
    aff[128+o] = fmaf(-mu, s, be[o]);
  }
}

// ---------------- pass 4: y1 -> bn1/relu -> conv2 (4 o-tiles) -> bn2/relu -> max_k -> out ----------------
__global__ __launch_bounds__(256, 4) void k_maxout(
    const float* __restrict__ y1, const float* __restrict__ aff1,
    const float* __restrict__ Wt2, const float* __restrict__ b2,
    const float* __restrict__ aff2, float* __restrict__ out)
{
  int tid = threadIdx.x;
  int j = tid & 31;                       // sample within node
  int node = blockIdx.x*8 + (tid >> 5);   // 8 nodes per block
  int col = node*32 + j;
  const float* yrow = y1 + (size_t)col*64;
  float x[64];
  #pragma unroll
  for (int c4 = 0; c4 < 64; c4 += 4) {
    float4 v = *(const float4*)(yrow + c4);
    x[c4]   = fmaxf(fmaf(v.x, aff1[c4],   aff1[128+c4]),   0.f);
    x[c4+1] = fmaxf(fmaf(v.y, aff1[c4+1], aff1[128+c4+1]), 0.f);
    x[c4+2] = fmaxf(fmaf(v.z, aff1[c4+2], aff1[128+c4+2]), 0.f);
    x[c4+3] = fmaxf(fmaf(v.w, aff1[c4+3], aff1[128+c4+3]), 0.f);
  }
  int b = node >> 11, m = node & 2047;
  float* op = out + ((size_t)b*128)*2048 + m;
  #pragma unroll
  for (int ot = 0; ot < 4; ++ot) {
    float acc[32];
    #pragma unroll
    for (int o = 0; o < 32; ++o) acc[o] = b2[ot*32 + o];
    #pragma unroll
    for (int c = 0; c < 64; ++c)
      #pragma unroll
      for (int o = 0; o < 32; ++o) acc[o] = fmaf(Wt2[c*128 + ot*32 + o], x[c], acc[o]);
    #pragma unroll
    for (int o = 0; o < 32; ++o) {
      int oo = ot*32 + o;
      float v = fmaxf(fmaf(acc[o], aff2[oo], aff2[128+oo]), 0.f);
      #pragma unroll
      for (int off = 1; off < 32; off <<= 1)
        v = fmaxf(v, __shfl_xor(v, off, 64));
      if (j == 0) op[(size_t)oo*2048] = v;
    }
  }
}

extern "C" void kernel_launch(void* const* d_in, const int* in_sizes, int n_in,
                              void* d_out, int out_size, void* d_ws, size_t ws_size,
                              hipStream_t stream)
{
  const float* xyz   = (const float*)d_in[0];
  const float* feats = (const float*)d_in[1];
  const float* W0 = (const float*)d_in[2];
  const float* b0 = (const float*)d_in[3];
  const float* g0 = (const float*)d_in[4];
  const float* be0= (const float*)d_in[5];
  const float* W1 = (const float*)d_in[6];
  const float* b1 = (const float*)d_in[7];
  const float* g1 = (const float*)d_in[8];
  const float* be1= (const float*)d_in[9];
  const float* W2 = (const float*)d_in[10];
  const float* b2 = (const float*)d_in[11];
  const float* g2 = (const float*)d_in[12];
  const float* be2= (const float*)d_in[13];

  char* ws = (char*)d_ws;
  float* sx    = (float*)(ws + OFF_SX);
  int*   knn   = (int*  )(ws + OFF_KNN);
  float* ft    = (float*)(ws + OFF_FT);
  float* stats = (float*)(ws + OFF_ST);
  float* aff   = (float*)(ws + OFF_AF);
  float* Wt0   = (float*)(ws + OFF_W0);
  float* Wt1   = (float*)(ws + OFF_W1);
  float* Wt2   = (float*)(ws + OFF_W2);
  float* y1    = (float*)(ws + OFF_Y1);

  float* centers_out = (float*)d_out;              // 8*2048*3
  float* feat_out    = (float*)d_out + NNODE*3;    // 8*128*2048

  k_prep<<<256, 256, 0, stream>>>(xyz, W0, W1, W2, sx, Wt0, Wt1, Wt2, stats, centers_out);
  k_ft  <<<1024, 256, 0, stream>>>(feats, ft);
  k_knn <<<NNODE/4, 256, 0, stream>>>(xyz, sx, knn);
  k_stat0<<<NCOL/256, 256, 0, stream>>>(xyz, ft, knn, Wt0, b0, stats + 0);
  k_fin  <<<1, 128, 0, stream>>>(stats + 0,   g0, be0, aff + 0,   64);
  k_l01  <<<NCOL/256, 256, 0, stream>>>(xyz, ft, knn, Wt0, b0, aff + 0, Wt1, b1, y1, stats + 256);
  k_fin  <<<1, 128, 0, stream>>>(stats + 256, g1, be1, aff + 256, 64);
  k_stat2<<<NCOL/256, 256, 0, stream>>>(y1, aff + 256, Wt2, b2, stats + 512);
  k_fin  <<<1, 128, 0, stream>>>(stats + 512, g2, be2, aff + 512, 128);
  k_maxout<<<NNODE/8, 256, 0, stream>>>(y1, aff + 256, Wt2, b2, aff + 512, feat_out);
}